// Round 6
// baseline (10324.635 us; speedup 1.0000x reference)
//
#include <hip/hip_runtime.h>
#include <hip/hip_bf16.h>

// LSTM B=32,T=512,D=512,H=1024, persistent kernel.
// R6 = R5 with the h-fragment tile1 offset bug fixed (q0+64 -> q0+256 ull;
// tile1 lives at +512 uints). R5 design recap:
//  - all-to-all store/poll barrier: block i stores epoch to flags[i] (64B
//    stride); wave 0 of each block polls all 64 flags in parallel (lane i
//    <-> flag i, __all). No atomic RMW, no tree hops, no s_sleep.
//  - direct sc1 h-stores from epilogue threads (no LDS stage).
//  - x-part MFMAs hoisted before the poll (waves 5-7 work while wave 0 polls).
//  - h loads double-buffered (issue kb+1 before MFMA kb) for latency overlap.

#define B_   32
#define T_   512
#define D_   512
#define H_   1024
#define KTOT 1536
#define N4H  4096
#define NBLK 64

typedef __bf16 bf16_t;
typedef __bf16 bf16x8 __attribute__((ext_vector_type(8)));
typedef float f32x4 __attribute__((ext_vector_type(4)));
typedef unsigned long long ull_t;

// ---------------------------------------------------------------------------
__global__ void wconv_kernel(const float* __restrict__ Wx,
                             const float* __restrict__ Wh,
                             bf16_t* __restrict__ Wt) {
    __shared__ float tile[32][33];
    int k0 = blockIdx.x * 32;
    int n0 = blockIdx.y * 32;
    int tx = threadIdx.x;
    int ty = threadIdx.y;
    for (int i = ty; i < 32; i += 8) {
        int k = k0 + i;
        float v = (k < H_) ? Wh[(size_t)k * N4H + n0 + tx]
                           : Wx[(size_t)(k - H_) * N4H + n0 + tx];
        tile[i][tx] = v;
    }
    __syncthreads();
    for (int i = ty; i < 32; i += 8)
        Wt[(size_t)(n0 + i) * KTOT + k0 + tx] = (bf16_t)tile[tx][i];
}

// ---------------------------------------------------------------------------
// X -> packed uint32 per element: low16 = bf16(hi), high16 = bf16(residual).
__global__ void xconv_kernel(const float4* __restrict__ X,
                             uint4* __restrict__ Xpk) {
    int i = blockIdx.x * blockDim.x + threadIdx.x;
    float4 v = X[i];
    float arr[4] = {v.x, v.y, v.z, v.w};
    unsigned pk[4];
#pragma unroll
    for (int j = 0; j < 4; ++j) {
        bf16_t h = (bf16_t)arr[j];
        bf16_t l = (bf16_t)(arr[j] - (float)h);
        pk[j] = (unsigned)__builtin_bit_cast(unsigned short, h) |
                ((unsigned)__builtin_bit_cast(unsigned short, l) << 16);
    }
    Xpk[i] = make_uint4(pk[0], pk[1], pk[2], pk[3]);
}

// ---------------------------------------------------------------------------
__device__ __forceinline__ void unpack16(const unsigned short* s,
                                         bf16x8* hi, bf16x8* lo) {
#pragma unroll
    for (int j = 0; j < 8; ++j) {
        (*hi)[j] = __builtin_bit_cast(bf16_t, s[2 * j]);
        (*lo)[j] = __builtin_bit_cast(bf16_t, s[2 * j + 1]);
    }
}

// x fragment: normal cacheable 2x dwordx4.
__device__ __forceinline__ void load_x_frag(const unsigned* p,
                                            bf16x8* hi, bf16x8* lo) {
    union { uint4 q[2]; unsigned short s[16]; } v;
    v.q[0] = *(const uint4*)p;
    v.q[1] = *(const uint4*)(p + 4);
    unpack16(v.s, hi, lo);
}

// ---------------------------------------------------------------------------
// Block b owns h-cols [16b,16b+16). Wave w = K-slice [192w,192w+192), all 4
// gates. hpk ping-pong, frag-major layout:
//   uint idx = (k>>5)*1024 + (b>>4)*512 + (((k>>3)&3)*16 + (b&15))*8 + (k&7)
__global__ __launch_bounds__(512, 2) void lstm_kernel(
    const bf16_t* __restrict__ Wt,
    const unsigned* __restrict__ Xpk,
    unsigned* __restrict__ hpk,
    const float* __restrict__ bias,
    const int* __restrict__ seqlen,
    float* __restrict__ out,
    unsigned* __restrict__ flags) {
    __shared__ float zpart[8][4][32][16];  // 64 KB: [slice][gate][batch][col]

    const int tid  = threadIdx.x;
    const int w    = tid >> 6;
    const int lane = tid & 63;
    const int quad = lane >> 4;
    const int lcol = lane & 15;
    const int hc0  = blockIdx.x * 16;
    const int HW_  = 32768;                // uints per h buffer (B_*H_)
    const int kbBase = w * 6;

    // Weight fragments: 4 gates x 6 k-iters, once.
    bf16x8 wreg[24];
#pragma unroll
    for (int g = 0; g < 4; ++g)
#pragma unroll
        for (int it = 0; it < 6; ++it)
            wreg[g * 6 + it] = *(const bf16x8*)(
                Wt + (size_t)(g * H_ + hc0 + lcol) * KTOT + w * 192 + it * 32 +
                quad * 8);

    // Epilogue mapping: 512 threads = one (batch,col) element each.
    const int eb = tid >> 4, ec = tid & 15;
    const int col = hc0 + ec;
    float creg = 0.f;
    const float b0 = bias[col];
    const float b1 = bias[H_ + col];
    const float b2 = bias[2 * H_ + col];
    const float b3 = bias[3 * H_ + col];
    const int slm1 = seqlen[eb] - 1;
    // Direct-store address in frag-major layout (fixed per thread).
    const int hidx = ((col >> 5) * 1024) + ((eb >> 4) * 512) +
                     ((((col >> 3) & 3) * 16 + (eb & 15)) * 8) + (col & 7);

    // Number of h-kbs this wave owns (kb < 32).
    int nh = 32 - kbBase;
    if (nh < 0) nh = 0;
    if (nh > 6) nh = 6;

#pragma unroll 1
    for (int t = 0; t < T_; ++t) {
        const unsigned* hr = hpk + (size_t)(t & 1) * HW_;
        unsigned*       hw = hpk + (size_t)((t + 1) & 1) * HW_;

        f32x4 acc[8];
#pragma unroll
        for (int i = 0; i < 8; ++i) acc[i] = (f32x4){0.f, 0.f, 0.f, 0.f};

        // -------- phase 1: x-part (kb >= 32) — independent of h(t) --------
#pragma unroll
        for (int it = 0; it < 6; ++it) {
            int kb = kbBase + it;
            if (kb >= 32) {
                int kx = kb * 32 - H_ + quad * 8;
                bf16x8 a0h, a0l, a1h, a1l;
                load_x_frag(Xpk + ((size_t)lcol * T_ + t) * D_ + kx, &a0h, &a0l);
                load_x_frag(Xpk + ((size_t)(lcol + 16) * T_ + t) * D_ + kx,
                            &a1h, &a1l);
#pragma unroll
                for (int g = 0; g < 4; ++g) {
                    bf16x8 wv = wreg[g * 6 + it];
                    acc[g * 2] = __builtin_amdgcn_mfma_f32_16x16x32_bf16(
                        a0h, wv, acc[g * 2], 0, 0, 0);
                    acc[g * 2] = __builtin_amdgcn_mfma_f32_16x16x32_bf16(
                        a0l, wv, acc[g * 2], 0, 0, 0);
                    acc[g * 2 + 1] = __builtin_amdgcn_mfma_f32_16x16x32_bf16(
                        a1h, wv, acc[g * 2 + 1], 0, 0, 0);
                    acc[g * 2 + 1] = __builtin_amdgcn_mfma_f32_16x16x32_bf16(
                        a1l, wv, acc[g * 2 + 1], 0, 0, 0);
                }
            }
        }

        // -------- barrier poll: wave 0 (pure-h wave) waits for h(t) --------
        if (tid < 64) {
            const unsigned* fp = flags + tid * 16;
            for (;;) {
                unsigned v = __hip_atomic_load(fp, __ATOMIC_RELAXED,
                                               __HIP_MEMORY_SCOPE_AGENT);
                if (__all((int)(v >= (unsigned)t))) break;
            }
        }
        __syncthreads();  // S1: h(t) visible to all waves

        // -------- phase 2: h-part (kb < 32), double-buffered loads --------
        // tile0 (batches 0..15) at q0+[0..3]; tile1 (batches 16..31) at
        // +512 uints = q0+256 ull.  (R5 bug: used +64.)
        ull_t raw[2][8];
        if (nh > 0) {
            const ull_t* q0 = (const ull_t*)(hr + kbBase * 1024 + lane * 8);
#pragma unroll
            for (int j = 0; j < 4; ++j) {
                raw[0][j] = __hip_atomic_load(q0 + j, __ATOMIC_RELAXED,
                                              __HIP_MEMORY_SCOPE_AGENT);
                raw[0][4 + j] = __hip_atomic_load(q0 + 256 + j, __ATOMIC_RELAXED,
                                                  __HIP_MEMORY_SCOPE_AGENT);
            }
        }
#pragma unroll 1
        for (int it = 0; it < nh; ++it) {
            if (it + 1 < nh) {
                const ull_t* q0 = (const ull_t*)(
                    hr + (kbBase + it + 1) * 1024 + lane * 8);
                int nb = (it + 1) & 1;
#pragma unroll
                for (int j = 0; j < 4; ++j) {
                    raw[nb][j] = __hip_atomic_load(
                        q0 + j, __ATOMIC_RELAXED, __HIP_MEMORY_SCOPE_AGENT);
                    raw[nb][4 + j] = __hip_atomic_load(
                        q0 + 256 + j, __ATOMIC_RELAXED, __HIP_MEMORY_SCOPE_AGENT);
                }
            }
            bf16x8 a0h, a0l, a1h, a1l;
            unpack16((const unsigned short*)&raw[it & 1][0], &a0h, &a0l);
            unpack16((const unsigned short*)&raw[it & 1][4], &a1h, &a1l);
#pragma unroll
            for (int g = 0; g < 4; ++g) {
                bf16x8 wv = wreg[g * 6 + it];
                acc[g * 2] = __builtin_amdgcn_mfma_f32_16x16x32_bf16(
                    a0h, wv, acc[g * 2], 0, 0, 0);
                acc[g * 2] = __builtin_amdgcn_mfma_f32_16x16x32_bf16(
                    a0l, wv, acc[g * 2], 0, 0, 0);
                acc[g * 2 + 1] = __builtin_amdgcn_mfma_f32_16x16x32_bf16(
                    a1h, wv, acc[g * 2 + 1], 0, 0, 0);
                acc[g * 2 + 1] = __builtin_amdgcn_mfma_f32_16x16x32_bf16(
                    a1l, wv, acc[g * 2 + 1], 0, 0, 0);
            }
        }

#pragma unroll
        for (int g = 0; g < 4; ++g)
#pragma unroll
            for (int r = 0; r < 4; ++r) {
                zpart[w][g][quad * 4 + r][lcol]      = acc[g * 2][r];
                zpart[w][g][16 + quad * 4 + r][lcol] = acc[g * 2 + 1][r];
            }
        __syncthreads();  // S2: zpart complete

        // -------- epilogue: all 512 threads, one (batch,col) each --------
        float zi = b0, zf = b1, zg = b2, zo = b3;
#pragma unroll
        for (int ss = 0; ss < 8; ++ss) {
            zi += zpart[ss][0][eb][ec];
            zf += zpart[ss][1][eb][ec];
            zg += zpart[ss][2][eb][ec];
            zo += zpart[ss][3][eb][ec];
        }
        float ig = 1.f / (1.f + __expf(-zi));
        float fg = 1.f / (1.f + __expf(-zf));
        float og = 1.f / (1.f + __expf(-zo));
        float gg = 1.f - 2.f / (__expf(2.f * zg) + 1.f);
        creg = fg * creg + ig * gg;
        float hn = og * (1.f - 2.f / (__expf(2.f * creg) + 1.f));
        bf16_t hh = (bf16_t)hn;
        bf16_t hl = (bf16_t)(hn - (float)hh);
        unsigned pk = (unsigned)__builtin_bit_cast(unsigned short, hh) |
                      ((unsigned)__builtin_bit_cast(unsigned short, hl) << 16);
        __hip_atomic_store(hw + hidx, pk, __ATOMIC_RELAXED,
                           __HIP_MEMORY_SCOPE_AGENT);
        if (slm1 == t) out[eb * H_ + col] = hn;

        // Drain h stores, block-wide, then signal arrival.
        asm volatile("s_waitcnt vmcnt(0)" ::: "memory");
        __syncthreads();  // S3: all waves' h stores at coherence point
        if (tid == 0)
            __hip_atomic_store(flags + blockIdx.x * 16, (unsigned)(t + 1),
                               __ATOMIC_RELAXED, __HIP_MEMORY_SCOPE_AGENT);
    }
}

// ---------------------------------------------------------------------------
extern "C" void kernel_launch(void* const* d_in, const int* in_sizes, int n_in,
                              void* d_out, int out_size, void* d_ws, size_t ws_size,
                              hipStream_t stream) {
    const float* inputs = (const float*)d_in[0];
    const int*   seqlen = (const int*)d_in[1];
    const float* Wx     = (const float*)d_in[2];
    const float* Wh     = (const float*)d_in[3];
    const float* bias   = (const float*)d_in[4];
    float* out = (float*)d_out;

    char* ws = (char*)d_ws;
    size_t o = 0;
    bf16_t*   Wt  = (bf16_t*)(ws + o);   o += (size_t)N4H * KTOT * 2;   // 12.6MB
    unsigned* Xpk = (unsigned*)(ws + o); o += (size_t)B_ * T_ * D_ * 4; // 33.6MB
    unsigned* hpk = (unsigned*)(ws + o); o += (size_t)2 * B_ * H_ * 4;  // 256KB
    unsigned* flg = (unsigned*)(ws + o); o += NBLK * 64;                // 4KB

    wconv_kernel<<<dim3(48, 128), dim3(32, 8), 0, stream>>>(Wx, Wh, Wt);
    xconv_kernel<<<(B_ * T_ * D_ / 4) / 256, 256, 0, stream>>>(
        (const float4*)inputs, (uint4*)Xpk);
    hipMemsetAsync(hpk, 0, (size_t)B_ * H_ * 4, stream);  // ping p=0 zeros
    hipMemsetAsync(flg, 0, NBLK * 64, stream);            // epoch flags = 0

    lstm_kernel<<<NBLK, 512, 0, stream>>>(Wt, Xpk, hpk, bias, seqlen, out, flg);
}

// Round 7
// 4493.526 us; speedup vs baseline: 2.2977x; 2.2977x over previous
//
#include <hip/hip_runtime.h>
#include <hip/hip_bf16.h>

// LSTM B=32,T=512,D=512,H=1024, persistent kernel.
// R7 = R4 body (best measured) + packed-flag store/poll barrier + x-phase
// hoisted before the poll.
//  - h frag-major layout; LDS-staged 8B h-stores (R4); fully-unrolled
//    compiler-pipelined h loads (R4).
//  - barrier: flags[64] contiguous uints (4 lines). Block i's tid0 stores
//    epoch t+1 to flags[i] after vmcnt-drain; wave 0 polls all 64 flags with
//    one 64-lane load (lane i <-> flags[i], __all(v>=t)). No RMW, no sleep.
//  - x-part (kb>=32) computed before the poll (waves 5-7 work while wave 0
//    polls); h-part after.

#define B_   32
#define T_   512
#define D_   512
#define H_   1024
#define KTOT 1536
#define N4H  4096
#define NBLK 64

typedef __bf16 bf16_t;
typedef __bf16 bf16x8 __attribute__((ext_vector_type(8)));
typedef float f32x4 __attribute__((ext_vector_type(4)));
typedef unsigned long long ull_t;

// ---------------------------------------------------------------------------
__global__ void wconv_kernel(const float* __restrict__ Wx,
                             const float* __restrict__ Wh,
                             bf16_t* __restrict__ Wt) {
    __shared__ float tile[32][33];
    int k0 = blockIdx.x * 32;
    int n0 = blockIdx.y * 32;
    int tx = threadIdx.x;
    int ty = threadIdx.y;
    for (int i = ty; i < 32; i += 8) {
        int k = k0 + i;
        float v = (k < H_) ? Wh[(size_t)k * N4H + n0 + tx]
                           : Wx[(size_t)(k - H_) * N4H + n0 + tx];
        tile[i][tx] = v;
    }
    __syncthreads();
    for (int i = ty; i < 32; i += 8)
        Wt[(size_t)(n0 + i) * KTOT + k0 + tx] = (bf16_t)tile[tx][i];
}

// ---------------------------------------------------------------------------
// X -> packed uint32 per element: low16 = bf16(hi), high16 = bf16(residual).
__global__ void xconv_kernel(const float4* __restrict__ X,
                             uint4* __restrict__ Xpk) {
    int i = blockIdx.x * blockDim.x + threadIdx.x;
    float4 v = X[i];
    float arr[4] = {v.x, v.y, v.z, v.w};
    unsigned pk[4];
#pragma unroll
    for (int j = 0; j < 4; ++j) {
        bf16_t h = (bf16_t)arr[j];
        bf16_t l = (bf16_t)(arr[j] - (float)h);
        pk[j] = (unsigned)__builtin_bit_cast(unsigned short, h) |
                ((unsigned)__builtin_bit_cast(unsigned short, l) << 16);
    }
    Xpk[i] = make_uint4(pk[0], pk[1], pk[2], pk[3]);
}

// ---------------------------------------------------------------------------
__device__ __forceinline__ void unpack16(const unsigned short* s,
                                         bf16x8* hi, bf16x8* lo) {
#pragma unroll
    for (int j = 0; j < 8; ++j) {
        (*hi)[j] = __builtin_bit_cast(bf16_t, s[2 * j]);
        (*lo)[j] = __builtin_bit_cast(bf16_t, s[2 * j + 1]);
    }
}

// h fragment: 32 B contiguous per lane (frag-major layout), 4x 8B sc1 loads.
__device__ __forceinline__ void load_h_frag(const unsigned* p,
                                            bf16x8* hi, bf16x8* lo) {
    union { unsigned long long u[4]; unsigned short s[16]; } v;
    const unsigned long long* q = (const unsigned long long*)p;
#pragma unroll
    for (int j = 0; j < 4; ++j)
        v.u[j] = __hip_atomic_load(q + j, __ATOMIC_RELAXED,
                                   __HIP_MEMORY_SCOPE_AGENT);
    unpack16(v.s, hi, lo);
}

// x fragment: normal cacheable 2x dwordx4.
__device__ __forceinline__ void load_x_frag(const unsigned* p,
                                            bf16x8* hi, bf16x8* lo) {
    union { uint4 q[2]; unsigned short s[16]; } v;
    v.q[0] = *(const uint4*)p;
    v.q[1] = *(const uint4*)(p + 4);
    unpack16(v.s, hi, lo);
}

// ---------------------------------------------------------------------------
// Block b owns h-cols [16b,16b+16). Wave w = K-slice [192w,192w+192), all 4
// gates. hpk ping-pong, frag-major layout:
//   uint idx = (k>>5)*1024 + (b>>4)*512 + (((k>>3)&3)*16 + (b&15))*8 + (k&7)
__global__ __launch_bounds__(512, 2) void lstm_kernel(
    const bf16_t* __restrict__ Wt,
    const unsigned* __restrict__ Xpk,
    unsigned* __restrict__ hpk,
    const float* __restrict__ bias,
    const int* __restrict__ seqlen,
    float* __restrict__ out,
    unsigned* __restrict__ flags) {
    __shared__ float zpart[8][4][32][16];  // 64 KB; tail reused as h-stage

    const int tid  = threadIdx.x;
    const int w    = tid >> 6;
    const int lane = tid & 63;
    const int quad = lane >> 4;
    const int lcol = lane & 15;
    const int hc0  = blockIdx.x * 16;
    const int HW_  = 32768;                // uints per h buffer (B_*H_)
    const int kbBase = w * 6;

    // Weight fragments: 4 gates x 6 k-iters, once.
    bf16x8 wreg[24];
#pragma unroll
    for (int g = 0; g < 4; ++g)
#pragma unroll
        for (int it = 0; it < 6; ++it)
            wreg[g * 6 + it] = *(const bf16x8*)(
                Wt + (size_t)(g * H_ + hc0 + lcol) * KTOT + w * 192 + it * 32 +
                quad * 8);

    // Epilogue mapping: 512 threads = one (batch,col) element each.
    const int eb = tid >> 4, ec = tid & 15;
    const int col = hc0 + ec;
    float creg = 0.f;
    const float b0 = bias[col];
    const float b1 = bias[H_ + col];
    const float b2 = bias[2 * H_ + col];
    const float b3 = bias[3 * H_ + col];
    const int slm1 = seqlen[eb] - 1;
    // LDS stage index (destination-ordered within this block's h region).
    const int stageIdx = (eb >> 4) * 256 + ((ec >> 3) * 16 + (eb & 15)) * 8 +
                         (ec & 7);
    // Store-phase constants (R4-verified).
    const int kbB  = (hc0 >> 5) * 1024;    // k-block base (uints)
    const int qlo  = (hc0 >> 4) & 1;       // which quad-pair within k-block
    const int dst0 = kbB + (tid >> 7) * 512 + qlo * 256 + (tid & 127) * 2;

#pragma unroll 1
    for (int t = 0; t < T_; ++t) {
        const unsigned* hr = hpk + (size_t)(t & 1) * HW_;
        unsigned*       hw = hpk + (size_t)((t + 1) & 1) * HW_;

        f32x4 acc[8];
#pragma unroll
        for (int i = 0; i < 8; ++i) acc[i] = (f32x4){0.f, 0.f, 0.f, 0.f};

        // -------- phase 1: x-part (kb >= 32) — independent of h(t) --------
#pragma unroll
        for (int it = 0; it < 6; ++it) {
            int kb = kbBase + it;
            if (kb >= 32) {
                int kx = kb * 32 - H_ + quad * 8;
                bf16x8 a0h, a0l, a1h, a1l;
                load_x_frag(Xpk + ((size_t)lcol * T_ + t) * D_ + kx, &a0h, &a0l);
                load_x_frag(Xpk + ((size_t)(lcol + 16) * T_ + t) * D_ + kx,
                            &a1h, &a1l);
#pragma unroll
                for (int g = 0; g < 4; ++g) {
                    bf16x8 wv = wreg[g * 6 + it];
                    acc[g * 2] = __builtin_amdgcn_mfma_f32_16x16x32_bf16(
                        a0h, wv, acc[g * 2], 0, 0, 0);
                    acc[g * 2] = __builtin_amdgcn_mfma_f32_16x16x32_bf16(
                        a0l, wv, acc[g * 2], 0, 0, 0);
                    acc[g * 2 + 1] = __builtin_amdgcn_mfma_f32_16x16x32_bf16(
                        a1h, wv, acc[g * 2 + 1], 0, 0, 0);
                    acc[g * 2 + 1] = __builtin_amdgcn_mfma_f32_16x16x32_bf16(
                        a1l, wv, acc[g * 2 + 1], 0, 0, 0);
                }
            }
        }

        // ---- barrier poll: packed flags, 4 lines, wave 0 only ----
        if (tid < 64) {
            for (;;) {
                unsigned v = __hip_atomic_load(flags + tid, __ATOMIC_RELAXED,
                                               __HIP_MEMORY_SCOPE_AGENT);
                if (__all((int)(v >= (unsigned)t))) break;
            }
        }
        __syncthreads();  // S1: h(t) visible to all waves

        // -------- phase 2: h-part (kb < 32), compiler-pipelined --------
#pragma unroll
        for (int it = 0; it < 6; ++it) {
            int kb = kbBase + it;
            if (kb < 32) {
                const unsigned* fb = hr + kb * 1024 + lane * 8;
                bf16x8 a0h, a0l, a1h, a1l;
                load_h_frag(fb,       &a0h, &a0l);   // batches 0..15
                load_h_frag(fb + 512, &a1h, &a1l);   // batches 16..31
#pragma unroll
                for (int g = 0; g < 4; ++g) {
                    bf16x8 wv = wreg[g * 6 + it];
                    acc[g * 2] = __builtin_amdgcn_mfma_f32_16x16x32_bf16(
                        a0h, wv, acc[g * 2], 0, 0, 0);
                    acc[g * 2] = __builtin_amdgcn_mfma_f32_16x16x32_bf16(
                        a0l, wv, acc[g * 2], 0, 0, 0);
                    acc[g * 2 + 1] = __builtin_amdgcn_mfma_f32_16x16x32_bf16(
                        a1h, wv, acc[g * 2 + 1], 0, 0, 0);
                    acc[g * 2 + 1] = __builtin_amdgcn_mfma_f32_16x16x32_bf16(
                        a1l, wv, acc[g * 2 + 1], 0, 0, 0);
                }
            }
        }

#pragma unroll
        for (int g = 0; g < 4; ++g)
#pragma unroll
            for (int r = 0; r < 4; ++r) {
                zpart[w][g][quad * 4 + r][lcol]      = acc[g * 2][r];
                zpart[w][g][16 + quad * 4 + r][lcol] = acc[g * 2 + 1][r];
            }
        __syncthreads();  // S2: zpart complete

        // -------- epilogue: all 512 threads, one (batch,col) each --------
        float zi = b0, zf = b1, zg = b2, zo = b3;
#pragma unroll
        for (int ss = 0; ss < 8; ++ss) {
            zi += zpart[ss][0][eb][ec];
            zf += zpart[ss][1][eb][ec];
            zg += zpart[ss][2][eb][ec];
            zo += zpart[ss][3][eb][ec];
        }
        float ig = 1.f / (1.f + __expf(-zi));
        float fg = 1.f / (1.f + __expf(-zf));
        float og = 1.f / (1.f + __expf(-zo));
        float gg = 1.f - 2.f / (__expf(2.f * zg) + 1.f);
        creg = fg * creg + ig * gg;
        float hn = og * (1.f - 2.f / (__expf(2.f * creg) + 1.f));
        bf16_t hh = (bf16_t)hn;
        bf16_t hl = (bf16_t)(hn - (float)hh);
        unsigned pk = (unsigned)__builtin_bit_cast(unsigned short, hh) |
                      ((unsigned)__builtin_bit_cast(unsigned short, hl) << 16);
        if (slm1 == t) out[eb * H_ + col] = hn;

        __syncthreads();  // S3: everyone done reading zpart -> reuse as stage
        unsigned* stage = (unsigned*)&zpart[0][0][0][0];
        stage[stageIdx] = pk;
        __syncthreads();  // S4: stage complete

        if (tid < 256) {
            unsigned long long val = ((const unsigned long long*)stage)[tid];
            __hip_atomic_store((unsigned long long*)(hw + dst0), val,
                               __ATOMIC_RELAXED, __HIP_MEMORY_SCOPE_AGENT);
        }

        // Drain h stores block-wide, then signal arrival.
        asm volatile("s_waitcnt vmcnt(0)" ::: "memory");
        __syncthreads();  // S5: all waves' h stores at coherence point
        if (tid == 0)
            __hip_atomic_store(flags + blockIdx.x, (unsigned)(t + 1),
                               __ATOMIC_RELAXED, __HIP_MEMORY_SCOPE_AGENT);
    }
}

// ---------------------------------------------------------------------------
extern "C" void kernel_launch(void* const* d_in, const int* in_sizes, int n_in,
                              void* d_out, int out_size, void* d_ws, size_t ws_size,
                              hipStream_t stream) {
    const float* inputs = (const float*)d_in[0];
    const int*   seqlen = (const int*)d_in[1];
    const float* Wx     = (const float*)d_in[2];
    const float* Wh     = (const float*)d_in[3];
    const float* bias   = (const float*)d_in[4];
    float* out = (float*)d_out;

    char* ws = (char*)d_ws;
    size_t o = 0;
    bf16_t*   Wt  = (bf16_t*)(ws + o);   o += (size_t)N4H * KTOT * 2;   // 12.6MB
    unsigned* Xpk = (unsigned*)(ws + o); o += (size_t)B_ * T_ * D_ * 4; // 33.6MB
    unsigned* hpk = (unsigned*)(ws + o); o += (size_t)2 * B_ * H_ * 4;  // 256KB
    unsigned* flg = (unsigned*)(ws + o); o += 256;                      // 64 uints

    wconv_kernel<<<dim3(48, 128), dim3(32, 8), 0, stream>>>(Wx, Wh, Wt);
    xconv_kernel<<<(B_ * T_ * D_ / 4) / 256, 256, 0, stream>>>(
        (const float4*)inputs, (uint4*)Xpk);
    hipMemsetAsync(hpk, 0, (size_t)B_ * H_ * 4, stream);  // ping p=0 zeros
    hipMemsetAsync(flg, 0, 256, stream);                  // epoch flags = 0

    lstm_kernel<<<NBLK, 512, 0, stream>>>(Wt, Xpk, hpk, bias, seqlen, out, flg);
}